// Round 1
// baseline (255.019 us; speedup 1.0000x reference)
//
#include <hip/hip_runtime.h>
#include <float.h>

#define HH 640
#define WW 640
#define KTOP 6
#define RR 4
#define CONF 0.3f
#define TX 64
#define TY 32
#define LXD (TX + 2*RR)   // 72
#define LYD (TY + 2*RR)   // 40
#define TILES_X (WW / TX)  // 10
#define TILES_Y (HH / TY)  // 20
#define TILES_PER_B (TILES_X * TILES_Y) // 200
#define CAP 128
#define NTHR 256
#define NWAVES (NTHR / 64)
#define MENT (TILES_PER_B * KTOP)  // 1200 entries per batch in merge

// ---------------- Kernel 1: tiled 9x9 NMS + per-block top-6 ----------------
__global__ __launch_bounds__(NTHR) void peaks_kernel(const float* __restrict__ hm,
                                                     float* __restrict__ bscore,
                                                     int* __restrict__ bidx) {
    __shared__ float s_in[LYD][LXD];     // input tile with halo
    __shared__ float s_hmax[LYD][TX];    // horizontal 1x9 max
    __shared__ float c_score[CAP];
    __shared__ int   c_idx[CAP];
    __shared__ int   c_count;
    __shared__ float r_score[NWAVES];
    __shared__ int   r_idx[NWAVES];
    __shared__ float win_s;
    __shared__ int   win_i;

    const int t  = threadIdx.x;
    const int b  = blockIdx.z;
    const int x0 = blockIdx.x * TX - RR;
    const int y0 = blockIdx.y * TY - RR;
    const float* img = hm + (size_t)b * HH * WW;

    if (t == 0) c_count = 0;
    __syncthreads();

    // ---- load tile (OOB = -FLT_MAX, matching -inf SAME padding) ----
    for (int e = t; e < LYD * LXD; e += NTHR) {
        int ly = e / LXD, lx = e - ly * LXD;
        int gy = y0 + ly, gx = x0 + lx;
        float v = -FLT_MAX;
        if (gy >= 0 && gy < HH && gx >= 0 && gx < WW) v = img[gy * WW + gx];
        s_in[ly][lx] = v;
    }
    __syncthreads();

    // ---- horizontal 1x9 max ----
    for (int e = t; e < LYD * TX; e += NTHR) {
        int ly = e / TX, lx = e - ly * TX;
        float m = s_in[ly][lx];
        #pragma unroll
        for (int j = 1; j <= 2 * RR; ++j) m = fmaxf(m, s_in[ly][lx + j]);
        s_hmax[ly][lx] = m;
    }
    __syncthreads();

    // ---- vertical 9x1 max + peak detect ----
    for (int e = t; e < TY * TX; e += NTHR) {
        int ly = e / TX, lx = e - ly * TX;
        float c = s_in[ly + RR][lx + RR];
        if (c > CONF) {
            float m = s_hmax[ly][lx];
            #pragma unroll
            for (int j = 1; j <= 2 * RR; ++j) m = fmaxf(m, s_hmax[ly + j][lx]);
            if (c >= m) {  // c == window max (max includes center so m >= c)
                int p = atomicAdd(&c_count, 1);
                if (p < CAP) {
                    c_score[p] = c;
                    c_idx[p]   = (y0 + RR + ly) * WW + (x0 + RR + lx);
                }
            }
        }
    }
    __syncthreads();

    const int cnt = min(c_count, CAP);
    const int outbase = (b * TILES_PER_B + blockIdx.y * TILES_X + blockIdx.x) * KTOP;

    // ---- 6-pass block argmax; total order: score desc, idx asc (lax.top_k ties) ----
    for (int k = 0; k < KTOP; ++k) {
        float s = -1.0f; int id = 0x7fffffff;
        if (t < cnt) { s = c_score[t]; id = c_idx[t]; }
        float rs = s; int rid = id;
        #pragma unroll
        for (int off = 32; off >= 1; off >>= 1) {
            float os = __shfl_xor(rs, off);
            int   oi = __shfl_xor(rid, off);
            if (os > rs || (os == rs && oi < rid)) { rs = os; rid = oi; }
        }
        const int wv = t >> 6;
        if ((t & 63) == 0) { r_score[wv] = rs; r_idx[wv] = rid; }
        __syncthreads();
        if (t == 0) {
            float bs = r_score[0]; int bi = r_idx[0];
            #pragma unroll
            for (int w2 = 1; w2 < NWAVES; ++w2) {
                if (r_score[w2] > bs || (r_score[w2] == bs && r_idx[w2] < bi)) {
                    bs = r_score[w2]; bi = r_idx[w2];
                }
            }
            win_s = bs; win_i = bi;
            bscore[outbase + k] = bs;
            bidx[outbase + k]   = bi;
        }
        __syncthreads();
        if (t < cnt && c_idx[t] == win_i) c_score[t] = -1.0f;  // remove winner
        __syncthreads();
    }
}

// ---------------- Kernel 2: per-batch merge of 1200 entries -> top-6 ----------------
__global__ __launch_bounds__(NTHR) void topk_kernel(const float* __restrict__ bscore,
                                                    const int* __restrict__ bidx,
                                                    float* __restrict__ out,
                                                    int B) {
    __shared__ float es[MENT];
    __shared__ int   ei[MENT];
    __shared__ float r_score[NWAVES];
    __shared__ int   r_idx[NWAVES];
    __shared__ float win_s[KTOP];
    __shared__ int   win_i[KTOP];

    const int t = threadIdx.x;
    const int b = blockIdx.x;

    for (int e = t; e < MENT; e += NTHR) {
        es[e] = bscore[b * MENT + e];
        ei[e] = bidx[b * MENT + e];
    }
    __syncthreads();

    for (int k = 0; k < KTOP; ++k) {
        float s = -2.0f; int id = 0x7fffffff;
        for (int e = t; e < MENT; e += NTHR) {
            float v = es[e]; int vi = ei[e];
            if (v > s || (v == s && vi < id)) { s = v; id = vi; }
        }
        float rs = s; int rid = id;
        #pragma unroll
        for (int off = 32; off >= 1; off >>= 1) {
            float os = __shfl_xor(rs, off);
            int   oi = __shfl_xor(rid, off);
            if (os > rs || (os == rs && oi < rid)) { rs = os; rid = oi; }
        }
        const int wv = t >> 6;
        if ((t & 63) == 0) { r_score[wv] = rs; r_idx[wv] = rid; }
        __syncthreads();
        if (t == 0) {
            float bs = r_score[0]; int bi = r_idx[0];
            #pragma unroll
            for (int w2 = 1; w2 < NWAVES; ++w2) {
                if (r_score[w2] > bs || (r_score[w2] == bs && r_idx[w2] < bi)) {
                    bs = r_score[w2]; bi = r_idx[w2];
                }
            }
            win_s[k] = bs; win_i[k] = bi;
        }
        __syncthreads();
        // remove winner (idx match; score match guards duplicate fill entries)
        for (int e = t; e < MENT; e += NTHR) {
            if (ei[e] == win_i[k] && es[e] == win_s[k]) es[e] = -2.0f;
        }
        __syncthreads();
    }

    if (t < KTOP) {
        float s = win_s[t]; int id = win_i[t];
        bool valid = (s > CONF) && (id < HH * WW) && (id >= 0);
        int xi = valid ? (id % WW) : 0;
        int yi = valid ? (id / WW) : 0;
        float px = valid ? xi * (1.0f / (WW - 1)) : -1.0f;
        float py = valid ? yi * (1.0f / (HH - 1)) : -1.0f;
        out[(size_t)b * KTOP * 2 + t * 2 + 0] = px;
        out[(size_t)b * KTOP * 2 + t * 2 + 1] = py;
        out[(size_t)B * KTOP * 2 + (size_t)b * KTOP + t] = valid ? s : 0.0f;
    }
}

extern "C" void kernel_launch(void* const* d_in, const int* in_sizes, int n_in,
                              void* d_out, int out_size, void* d_ws, size_t ws_size,
                              hipStream_t stream) {
    const float* hm = (const float*)d_in[0];
    float* out = (float*)d_out;
    const int B = in_sizes[0] / (HH * WW);

    float* bscore = (float*)d_ws;
    int*   bidx   = (int*)((char*)d_ws + sizeof(float) * (size_t)B * TILES_PER_B * KTOP);

    dim3 grid1(TILES_X, TILES_Y, B);
    peaks_kernel<<<grid1, NTHR, 0, stream>>>(hm, bscore, bidx);
    topk_kernel<<<B, NTHR, 0, stream>>>(bscore, bidx, out, B);
}

// Round 2
// 209.411 us; speedup vs baseline: 1.2178x; 1.2178x over previous
//
#include <hip/hip_runtime.h>
#include <float.h>

#define HH 640
#define WW 640
#define KTOP 6
#define RR 4
#define CONF 0.3f

#define TX 128
#define TY 32
#define V 4                        // output rows per vmax strip task
#define GG ((TX + 2*RR) / 4)       // 34 float4 col-groups (1 halo group each side)
#define BANDS (TY / V)             // 8
#define NTASK (GG * BANDS)         // 272
#define NTHR 256
#define NWAVES (NTHR / 64)
#define TILES_X (WW / TX)          // 5
#define TILES_Y (HH / TY)          // 20
#define TILES_PER_B (TILES_X * TILES_Y)  // 100
#define CAP 128
#define MENT (TILES_PER_B * KTOP)  // 600 entries per batch in merge

__device__ __forceinline__ float4 f4max(float4 a, float4 b) {
    return make_float4(fmaxf(a.x, b.x), fmaxf(a.y, b.y), fmaxf(a.z, b.z), fmaxf(a.w, b.w));
}

// ---------------- Kernel 1: 9x9 NMS via separable max (regs + b128 LDS) ----------------
__global__ __launch_bounds__(NTHR) void peaks_kernel(const float* __restrict__ hm,
                                                     float* __restrict__ bscore,
                                                     int* __restrict__ bidx) {
    __shared__ float vmax[TY][GG * 4];   // [32][136] = 17.4 KB, vertical 9-max w/ x-halo
    __shared__ float c_score[CAP];
    __shared__ int   c_idx[CAP];
    __shared__ int   c_count;

    const int t  = threadIdx.x;
    const int b  = blockIdx.z;
    const int x0 = blockIdx.x * TX;
    const int y0 = blockIdx.y * TY;
    const float* img = hm + (size_t)b * (HH * WW);

    if (t == 0) c_count = 0;

    // ---- phase 1: vertical sliding 9-max in registers, write b128 to LDS ----
    for (int task = t; task < NTASK; task += NTHR) {
        const int band = task / GG;
        const int gg   = task - band * GG;
        const int gxf  = x0 + gg * 4 - RR;   // float col of this group's start
        const int ry0  = band * V;           // local output row start
        float4 v[V + 2 * RR];                // 12 rows
        const float4 NEG = make_float4(-FLT_MAX, -FLT_MAX, -FLT_MAX, -FLT_MAX);
        if (gxf >= 0 && gxf < WW) {          // x-halo groups are fully in or fully out
            const float* col = img + gxf;
            #pragma unroll
            for (int j = 0; j < V + 2 * RR; ++j) {
                const int gy = y0 + ry0 - RR + j;
                v[j] = (gy >= 0 && gy < HH)
                       ? *reinterpret_cast<const float4*>(col + (size_t)gy * WW)
                       : NEG;
            }
        } else {
            #pragma unroll
            for (int j = 0; j < V + 2 * RR; ++j) v[j] = NEG;
        }
        // windows: out[i] = max(v[i..i+8]), i=0..3 ; shared core = max(v[3..8])
        float4 core = f4max(f4max(f4max(v[3], v[4]), f4max(v[5], v[6])), f4max(v[7], v[8]));
        float4 a  = f4max(v[1], v[2]);
        float4 bb = f4max(v[9], v[10]);
        float4 m0 = f4max(core, f4max(v[0], a));
        float4 m1 = f4max(core, f4max(a, v[9]));
        float4 m2 = f4max(core, f4max(v[2], bb));
        float4 m3 = f4max(core, f4max(bb, v[11]));
        *reinterpret_cast<float4*>(&vmax[ry0 + 0][gg * 4]) = m0;
        *reinterpret_cast<float4*>(&vmax[ry0 + 1][gg * 4]) = m1;
        *reinterpret_cast<float4*>(&vmax[ry0 + 2][gg * 4]) = m2;
        *reinterpret_cast<float4*>(&vmax[ry0 + 3][gg * 4]) = m3;
    }
    __syncthreads();

    // ---- phase 2: horizontal sliding 9-max in registers + peak detect ----
    for (int g = t; g < (TY * TX / 4); g += NTHR) {
        const int ly = g >> 5;               // TX/4 = 32 groups per row
        const int lx = (g & 31) * 4;         // float col within tile
        const float* row = &vmax[ly][0];
        float4 p0 = *reinterpret_cast<const float4*>(row + lx);
        float4 p1 = *reinterpret_cast<const float4*>(row + lx + 4);
        float4 p2 = *reinterpret_cast<const float4*>(row + lx + 8);
        const float v0 = p0.x, v1 = p0.y, v2 = p0.z,  v3 = p0.w;
        const float v4 = p1.x, v5 = p1.y, v6 = p1.z,  v7 = p1.w;
        const float v8 = p2.x, v9 = p2.y, v10 = p2.z, v11 = p2.w;
        const float core = fmaxf(fmaxf(fmaxf(v3, v4), fmaxf(v5, v6)), fmaxf(v7, v8));
        const float a  = fmaxf(v1, v2);
        const float bb = fmaxf(v9, v10);
        const float m0 = fmaxf(core, fmaxf(v0, a));
        const float m1 = fmaxf(core, fmaxf(a, v9));
        const float m2 = fmaxf(core, fmaxf(v2, bb));
        const float m3 = fmaxf(core, fmaxf(bb, v11));
        const int gy = y0 + ly, gx = x0 + lx;
        const float4 c = *reinterpret_cast<const float4*>(img + (size_t)gy * WW + gx);
        const int base = gy * WW + gx;
        if (c.x > CONF && c.x >= m0) { int p = atomicAdd(&c_count, 1); if (p < CAP) { c_score[p] = c.x; c_idx[p] = base;     } }
        if (c.y > CONF && c.y >= m1) { int p = atomicAdd(&c_count, 1); if (p < CAP) { c_score[p] = c.y; c_idx[p] = base + 1; } }
        if (c.z > CONF && c.z >= m2) { int p = atomicAdd(&c_count, 1); if (p < CAP) { c_score[p] = c.z; c_idx[p] = base + 2; } }
        if (c.w > CONF && c.w >= m3) { int p = atomicAdd(&c_count, 1); if (p < CAP) { c_score[p] = c.w; c_idx[p] = base + 3; } }
    }
    __syncthreads();

    // ---- single-wave top-6: wave 0, 2 candidates/lane, 6 butterfly argmax passes ----
    if (t < 64) {
        const int cnt = min(c_count, CAP);
        const int outbase = (b * TILES_PER_B + blockIdx.y * TILES_X + blockIdx.x) * KTOP;
        float s0 = (t      < cnt) ? c_score[t]      : -2.0f;
        int   i0 = (t      < cnt) ? c_idx[t]        : 0x7fffffff;
        float s1 = (t + 64 < cnt) ? c_score[t + 64] : -2.0f;
        int   i1 = (t + 64 < cnt) ? c_idx[t + 64]   : 0x7fffffff;
        #pragma unroll
        for (int k = 0; k < KTOP; ++k) {
            float bs; int bi;
            if (s0 > s1 || (s0 == s1 && i0 < i1)) { bs = s0; bi = i0; } else { bs = s1; bi = i1; }
            #pragma unroll
            for (int off = 32; off >= 1; off >>= 1) {
                const float os = __shfl_xor(bs, off);
                const int   oi = __shfl_xor(bi, off);
                if (os > bs || (os == bs && oi < bi)) { bs = os; bi = oi; }
            }
            if (t == 0) { bscore[outbase + k] = bs; bidx[outbase + k] = bi; }
            if (i0 == bi) s0 = -3.0f;   // idx unique among real candidates
            if (i1 == bi) s1 = -3.0f;
        }
    }
}

// ---------------- Kernel 2: per-batch merge of 600 entries -> top-6 ----------------
__global__ __launch_bounds__(NTHR) void topk_kernel(const float* __restrict__ bscore,
                                                    const int* __restrict__ bidx,
                                                    float* __restrict__ out,
                                                    int B) {
    __shared__ float es[MENT];
    __shared__ int   ei[MENT];
    __shared__ float r_score[NWAVES];
    __shared__ int   r_idx[NWAVES];
    __shared__ float win_s[KTOP];
    __shared__ int   win_i[KTOP];

    const int t = threadIdx.x;
    const int b = blockIdx.x;

    for (int e = t; e < MENT; e += NTHR) {
        es[e] = bscore[b * MENT + e];
        ei[e] = bidx[b * MENT + e];
    }
    __syncthreads();

    for (int k = 0; k < KTOP; ++k) {
        float s = -9.0f; int id = 0x7fffffff;
        for (int e = t; e < MENT; e += NTHR) {
            const float v = es[e]; const int vi = ei[e];
            if (v > s || (v == s && vi < id)) { s = v; id = vi; }
        }
        float rs = s; int rid = id;
        #pragma unroll
        for (int off = 32; off >= 1; off >>= 1) {
            const float os = __shfl_xor(rs, off);
            const int   oi = __shfl_xor(rid, off);
            if (os > rs || (os == rs && oi < rid)) { rs = os; rid = oi; }
        }
        const int wv = t >> 6;
        if ((t & 63) == 0) { r_score[wv] = rs; r_idx[wv] = rid; }
        __syncthreads();
        if (t == 0) {
            float bs = r_score[0]; int bi = r_idx[0];
            #pragma unroll
            for (int w2 = 1; w2 < NWAVES; ++w2) {
                if (r_score[w2] > bs || (r_score[w2] == bs && r_idx[w2] < bi)) {
                    bs = r_score[w2]; bi = r_idx[w2];
                }
            }
            win_s[k] = bs; win_i[k] = bi;
        }
        __syncthreads();
        for (int e = t; e < MENT; e += NTHR) {
            if (ei[e] == win_i[k] && es[e] == win_s[k]) es[e] = -9.0f;
        }
        __syncthreads();
    }

    if (t < KTOP) {
        const float s = win_s[t]; const int id = win_i[t];
        const bool valid = (s > CONF) && (id < HH * WW) && (id >= 0);
        const int xi = valid ? (id % WW) : 0;
        const int yi = valid ? (id / WW) : 0;
        const float px = valid ? xi * (1.0f / (WW - 1)) : -1.0f;
        const float py = valid ? yi * (1.0f / (HH - 1)) : -1.0f;
        out[(size_t)b * KTOP * 2 + t * 2 + 0] = px;
        out[(size_t)b * KTOP * 2 + t * 2 + 1] = py;
        out[(size_t)B * KTOP * 2 + (size_t)b * KTOP + t] = valid ? s : 0.0f;
    }
}

extern "C" void kernel_launch(void* const* d_in, const int* in_sizes, int n_in,
                              void* d_out, int out_size, void* d_ws, size_t ws_size,
                              hipStream_t stream) {
    const float* hm = (const float*)d_in[0];
    float* out = (float*)d_out;
    const int B = in_sizes[0] / (HH * WW);

    float* bscore = (float*)d_ws;
    int*   bidx   = (int*)((char*)d_ws + sizeof(float) * (size_t)B * MENT);

    dim3 grid1(TILES_X, TILES_Y, B);
    peaks_kernel<<<grid1, NTHR, 0, stream>>>(hm, bscore, bidx);
    topk_kernel<<<B, NTHR, 0, stream>>>(bscore, bidx, out, B);
}

// Round 3
// 172.558 us; speedup vs baseline: 1.4779x; 1.2136x over previous
//
#include <hip/hip_runtime.h>
#include <float.h>

#define HH 640
#define WW 640
#define KTOP 6
#define CONF 0.3f
#define NTHR 256
#define ROWS_PER_WAVE 32
#define ROWS_PER_BLOCK 128          // 4 waves * 32 rows
#define XBANDS 3
#define XOUT 248                    // valid output cols per band (lanes 1..62)
#define YCHUNKS (HH / ROWS_PER_BLOCK)     // 5
#define TILES_PER_B (XBANDS * YCHUNKS)    // 15
#define MENT (TILES_PER_B * KTOP)         // 90
#define CAP 512

__device__ __forceinline__ float4 f4max(float4 a, float4 b) {
    return make_float4(fmaxf(a.x, b.x), fmaxf(a.y, b.y), fmaxf(a.z, b.z), fmaxf(a.w, b.w));
}

// ---------------- Kernel 1: register-streaming 9x9 NMS + per-block top-6 ----------------
__global__ __launch_bounds__(NTHR, 4) void peaks_kernel(const float* __restrict__ hm,
                                                        float* __restrict__ bscore,
                                                        int* __restrict__ bidx) {
    __shared__ float c_score[CAP];
    __shared__ int   c_idx[CAP];
    __shared__ int   c_count;

    const int t    = threadIdx.x;
    const int lane = t & 63;
    const int w    = t >> 6;
    const int b    = blockIdx.z;
    const int xb0  = blockIdx.x * XOUT;
    const int yw0  = blockIdx.y * ROWS_PER_BLOCK + w * ROWS_PER_WAVE;
    const int x    = xb0 - 4 + 4 * lane;          // this lane's 4 columns (load + output)
    const bool xok = (x >= 0) && (x + 3 < WW);
    const bool vlane = (lane >= 1) && (lane <= 62) && xok;   // producing valid output
    const float* img = hm + (size_t)b * (HH * WW);
    const float4 NEG = make_float4(-FLT_MAX, -FLT_MAX, -FLT_MAX, -FLT_MAX);

    if (t == 0) c_count = 0;
    __syncthreads();

    // ring: p0..p7 = input rows R-4..R+3 (R = current chunk's first output row)
    float4 p0, p1, p2, p3, p4, p5, p6, p7;
    {
        const float* colp = img + x;
        #define LOADROW(dst, yy) { const int gy = (yy); \
            dst = (xok && gy >= 0 && gy < HH) ? *reinterpret_cast<const float4*>(colp + (size_t)gy * WW) : NEG; }
        LOADROW(p0, yw0 - 4) LOADROW(p1, yw0 - 3) LOADROW(p2, yw0 - 2) LOADROW(p3, yw0 - 1)
        LOADROW(p4, yw0 + 0) LOADROW(p5, yw0 + 1) LOADROW(p6, yw0 + 2) LOADROW(p7, yw0 + 3)

        for (int k = 0; k < 8; ++k) {
            const int R = yw0 + 4 * k;
            float4 n0, n1, n2, n3;
            LOADROW(n0, R + 4) LOADROW(n1, R + 5) LOADROW(n2, R + 6) LOADROW(n3, R + 7)

            // vertical sliding 9-max for output rows R..R+3 (v0..v11 = p0..p7,n0..n3)
            const float4 core = f4max(f4max(f4max(p3, p4), f4max(p5, p6)), f4max(p7, n0));
            const float4 a    = f4max(p1, p2);
            const float4 bb   = f4max(n1, n2);
            float4 vm[1]; // (avoid array) -- use named:
            const float4 m0 = f4max(core, f4max(p0, a));
            const float4 m1 = f4max(core, f4max(a, n1));
            const float4 m2 = f4max(core, f4max(p2, bb));
            const float4 m3 = f4max(core, f4max(bb, n3));
            (void)vm;

            // horizontal 9-max via wave shuffles; centers are p4..p7 (rows R..R+3)
            #define PROCROW(m, c, gy_) { \
                const float w0 = __shfl_up(m.x, 1),  w1 = __shfl_up(m.y, 1); \
                const float w2 = __shfl_up(m.z, 1),  w3 = __shfl_up(m.w, 1); \
                const float w8 = __shfl_down(m.x, 1), w9 = __shfl_down(m.y, 1); \
                const float wA = __shfl_down(m.z, 1), wB = __shfl_down(m.w, 1); \
                const float hc = fmaxf(fmaxf(fmaxf(w3, m.x), fmaxf(m.y, m.z)), fmaxf(m.w, w8)); \
                const float ha = fmaxf(w1, w2); \
                const float hb = fmaxf(w9, wA); \
                const float h0 = fmaxf(hc, fmaxf(w0, ha)); \
                const float h1 = fmaxf(hc, fmaxf(ha, w9)); \
                const float h2 = fmaxf(hc, fmaxf(w2, hb)); \
                const float h3 = fmaxf(hc, fmaxf(hb, wB)); \
                if (vlane) { \
                    const int base = (gy_) * WW + x; \
                    if (c.x > CONF && c.x >= h0) { int p = atomicAdd(&c_count, 1); if (p < CAP) { c_score[p] = c.x; c_idx[p] = base;     } } \
                    if (c.y > CONF && c.y >= h1) { int p = atomicAdd(&c_count, 1); if (p < CAP) { c_score[p] = c.y; c_idx[p] = base + 1; } } \
                    if (c.z > CONF && c.z >= h2) { int p = atomicAdd(&c_count, 1); if (p < CAP) { c_score[p] = c.z; c_idx[p] = base + 2; } } \
                    if (c.w > CONF && c.w >= h3) { int p = atomicAdd(&c_count, 1); if (p < CAP) { c_score[p] = c.w; c_idx[p] = base + 3; } } \
                } \
            }
            PROCROW(m0, p4, R + 0)
            PROCROW(m1, p5, R + 1)
            PROCROW(m2, p6, R + 2)
            PROCROW(m3, p7, R + 3)

            // rotate ring: p <- rows R..R+7
            p0 = p4; p1 = p5; p2 = p6; p3 = p7;
            p4 = n0; p5 = n1; p6 = n2; p7 = n3;
        }
    }
    __syncthreads();

    // ---- single-wave top-6 (wave 0, 8 candidates per lane) ----
    if (w == 0) {
        const int cnt = min(c_count, CAP);
        float cs[8]; int ci[8];
        #pragma unroll
        for (int j = 0; j < 8; ++j) {
            const int p = lane + 64 * j;
            const bool ok = p < cnt;
            cs[j] = ok ? c_score[p] : -2.0f;
            ci[j] = ok ? c_idx[p]   : 0x7fffffff;
        }
        const int outbase = (b * TILES_PER_B + blockIdx.y * XBANDS + blockIdx.x) * KTOP;
        #pragma unroll
        for (int k = 0; k < KTOP; ++k) {
            float bs = cs[0]; int bi = ci[0];
            #pragma unroll
            for (int j = 1; j < 8; ++j)
                if (cs[j] > bs || (cs[j] == bs && ci[j] < bi)) { bs = cs[j]; bi = ci[j]; }
            #pragma unroll
            for (int off = 32; off >= 1; off >>= 1) {
                const float os = __shfl_xor(bs, off);
                const int   oi = __shfl_xor(bi, off);
                if (os > bs || (os == bs && oi < bi)) { bs = os; bi = oi; }
            }
            if (lane == 0) { bscore[outbase + k] = bs; bidx[outbase + k] = bi; }
            #pragma unroll
            for (int j = 0; j < 8; ++j) if (ci[j] == bi) cs[j] = -3.0f;
        }
    }
}

// ---------------- Kernel 2: per-batch merge of 90 entries -> top-6 (1 wave) ----------------
__global__ __launch_bounds__(64) void topk_kernel(const float* __restrict__ bscore,
                                                  const int* __restrict__ bidx,
                                                  float* __restrict__ out,
                                                  int B) {
    const int t = threadIdx.x;   // 64 threads
    const int b = blockIdx.x;

    float s0 = -9.0f; int i0 = 0x7fffffff;
    float s1 = -9.0f; int i1 = 0x7fffffff;
    if (t < MENT)      { s0 = bscore[b * MENT + t];      i0 = bidx[b * MENT + t]; }
    if (t + 64 < MENT) { s1 = bscore[b * MENT + t + 64]; i1 = bidx[b * MENT + t + 64]; }

    float my_s = -9.0f; int my_i = 0x7fffffff;
    #pragma unroll
    for (int k = 0; k < KTOP; ++k) {
        float bs; int bi;
        if (s0 > s1 || (s0 == s1 && i0 < i1)) { bs = s0; bi = i0; } else { bs = s1; bi = i1; }
        #pragma unroll
        for (int off = 32; off >= 1; off >>= 1) {
            const float os = __shfl_xor(bs, off);
            const int   oi = __shfl_xor(bi, off);
            if (os > bs || (os == bs && oi < bi)) { bs = os; bi = oi; }
        }
        if (t == k) { my_s = bs; my_i = bi; }   // thread k owns result k
        if (i0 == bi) s0 = -9.0f;
        if (i1 == bi) s1 = -9.0f;
    }

    if (t < KTOP) {
        const bool valid = (my_s > CONF) && (my_i >= 0) && (my_i < HH * WW);
        const int id = valid ? my_i : 0;
        const int xi = id % WW;
        const int yi = id / WW;
        const float px = valid ? xi * (1.0f / (WW - 1)) : -1.0f;
        const float py = valid ? yi * (1.0f / (HH - 1)) : -1.0f;
        out[(size_t)b * KTOP * 2 + t * 2 + 0] = px;
        out[(size_t)b * KTOP * 2 + t * 2 + 1] = py;
        out[(size_t)B * KTOP * 2 + (size_t)b * KTOP + t] = valid ? my_s : 0.0f;
    }
}

extern "C" void kernel_launch(void* const* d_in, const int* in_sizes, int n_in,
                              void* d_out, int out_size, void* d_ws, size_t ws_size,
                              hipStream_t stream) {
    const float* hm = (const float*)d_in[0];
    float* out = (float*)d_out;
    const int B = in_sizes[0] / (HH * WW);

    float* bscore = (float*)d_ws;
    int*   bidx   = (int*)((char*)d_ws + sizeof(float) * (size_t)B * MENT);

    dim3 grid1(XBANDS, YCHUNKS, B);
    peaks_kernel<<<grid1, NTHR, 0, stream>>>(hm, bscore, bidx);
    topk_kernel<<<B, 64, 0, stream>>>(bscore, bidx, out, B);
}

// Round 5
// 164.655 us; speedup vs baseline: 1.5488x; 1.0480x over previous
//
#include <hip/hip_runtime.h>
#include <float.h>

#define HH 640
#define WW 640
#define KTOP 6
#define CONF 0.3f
#define NTHR 256
#define ROWS_W 16                         // output rows per wave
#define ROWS_B (ROWS_W * 4)               // 64 rows per block
#define XBANDS 3
#define XOUT 248                          // valid output cols per band (lanes 1..62)
#define YCH (HH / ROWS_B)                 // 10
#define TILES_PER_B (XBANDS * YCH)        // 30
#define MENT (TILES_PER_B * KTOP)         // 180
#define CAP 512

__device__ __forceinline__ float4 f4max(float4 a, float4 b) {
    return make_float4(fmaxf(a.x, b.x), fmaxf(a.y, b.y), fmaxf(a.z, b.z), fmaxf(a.w, b.w));
}

// ---------------- Kernel 1: register-streaming 9x9 NMS, batched loads ----------------
__global__ __launch_bounds__(NTHR, 3) void peaks_kernel(const float* __restrict__ hm,
                                                        float* __restrict__ bscore,
                                                        int* __restrict__ bidx) {
    __shared__ float c_score[CAP];
    __shared__ int   c_idx[CAP];
    __shared__ int   c_count;

    const int t     = threadIdx.x;
    const int lane  = t & 63;
    const int w     = t >> 6;
    const int b     = blockIdx.z;
    const int xb0   = blockIdx.x * XOUT;
    const int yw0   = blockIdx.y * ROWS_B + w * ROWS_W;
    const int x_raw = xb0 - 4 + 4 * lane;
    const int xc    = x_raw < 0 ? 0 : (x_raw > WW - 4 ? WW - 4 : x_raw);
    const bool xok  = (x_raw >= 0) && (x_raw <= WW - 4);
    const bool vlane = (lane >= 1) && (lane <= 62) && xok;
    const float* img  = hm + (size_t)b * (HH * WW);
    const float* colp = img + xc;
    const float4 NEG  = make_float4(-FLT_MAX, -FLT_MAX, -FLT_MAX, -FLT_MAX);

    if (t == 0) c_count = 0;
    __syncthreads();

    // ---- 24 unconditional clamped-row loads (rows yw0-4 .. yw0+19) ----
    // row clamp = edge replication: exact for sliding max with -inf SAME padding
    float4 r0, r1, r2, r3, r4, r5, r6, r7, r8, r9, r10, r11,
           r12, r13, r14, r15, r16, r17, r18, r19, r20, r21, r22, r23;
    #define LDR(i, dst) { int gy = yw0 - 4 + (i); \
        gy = gy < 0 ? 0 : (gy > HH - 1 ? HH - 1 : gy); \
        dst = *reinterpret_cast<const float4*>(colp + (size_t)gy * WW); }
    LDR(0,  r0)  LDR(1,  r1)  LDR(2,  r2)  LDR(3,  r3)
    LDR(4,  r4)  LDR(5,  r5)  LDR(6,  r6)  LDR(7,  r7)
    LDR(8,  r8)  LDR(9,  r9)  LDR(10, r10) LDR(11, r11)
    LDR(12, r12) LDR(13, r13) LDR(14, r14) LDR(15, r15)
    LDR(16, r16) LDR(17, r17) LDR(18, r18) LDR(19, r19)
    LDR(20, r20) LDR(21, r21) LDR(22, r22) LDR(23, r23)

    // horizontal 9-max + peak detect for one output row (m = this lane's vertical max)
    #define PROCROW(m, c, gy_) { \
        const float w0 = __shfl_up(m.x, 1),  w1 = __shfl_up(m.y, 1); \
        const float w2 = __shfl_up(m.z, 1),  w3 = __shfl_up(m.w, 1); \
        const float w8 = __shfl_down(m.x, 1), w9 = __shfl_down(m.y, 1); \
        const float wA = __shfl_down(m.z, 1), wB = __shfl_down(m.w, 1); \
        const float hc = fmaxf(fmaxf(fmaxf(w3, m.x), fmaxf(m.y, m.z)), fmaxf(m.w, w8)); \
        const float ha = fmaxf(w1, w2); \
        const float hb = fmaxf(w9, wA); \
        const float h0 = fmaxf(hc, fmaxf(w0, ha)); \
        const float h1 = fmaxf(hc, fmaxf(ha, w9)); \
        const float h2 = fmaxf(hc, fmaxf(w2, hb)); \
        const float h3 = fmaxf(hc, fmaxf(hb, wB)); \
        if (vlane) { \
            const int base = (gy_) * WW + x_raw; \
            if (c.x > CONF && c.x >= h0) { int p = atomicAdd(&c_count, 1); if (p < CAP) { c_score[p] = c.x; c_idx[p] = base;     } } \
            if (c.y > CONF && c.y >= h1) { int p = atomicAdd(&c_count, 1); if (p < CAP) { c_score[p] = c.y; c_idx[p] = base + 1; } } \
            if (c.z > CONF && c.z >= h2) { int p = atomicAdd(&c_count, 1); if (p < CAP) { c_score[p] = c.z; c_idx[p] = base + 2; } } \
            if (c.w > CONF && c.w >= h3) { int p = atomicAdd(&c_count, 1); if (p < CAP) { c_score[p] = c.w; c_idx[p] = base + 3; } } \
        } \
    }

    // vertical sliding 9-max over 12 rows -> 4 output rows, then horizontal
    #define VCHUNK(A0,A1,A2,A3,A4,A5,A6,A7,A8,A9,A10,A11, R) { \
        float4 core = f4max(f4max(f4max(A3, A4), f4max(A5, A6)), f4max(A7, A8)); \
        float4 pa = f4max(A1, A2); \
        float4 pb = f4max(A9, A10); \
        float4 m0 = f4max(core, f4max(A0, pa)); \
        float4 m1 = f4max(core, f4max(pa, A9)); \
        float4 m2 = f4max(core, f4max(A2, pb)); \
        float4 m3 = f4max(core, f4max(pb, A11)); \
        if (!xok) { m0 = NEG; m1 = NEG; m2 = NEG; m3 = NEG; } \
        PROCROW(m0, A4, (R) + 0) \
        PROCROW(m1, A5, (R) + 1) \
        PROCROW(m2, A6, (R) + 2) \
        PROCROW(m3, A7, (R) + 3) \
    }

    VCHUNK(r0,  r1,  r2,  r3,  r4,  r5,  r6,  r7,  r8,  r9,  r10, r11, yw0 + 0)
    VCHUNK(r4,  r5,  r6,  r7,  r8,  r9,  r10, r11, r12, r13, r14, r15, yw0 + 4)
    VCHUNK(r8,  r9,  r10, r11, r12, r13, r14, r15, r16, r17, r18, r19, yw0 + 8)
    VCHUNK(r12, r13, r14, r15, r16, r17, r18, r19, r20, r21, r22, r23, yw0 + 12)

    __syncthreads();

    // ---- single-wave top-6 (wave 0, 8 candidates per lane) ----
    if (w == 0) {
        const int cnt = min(c_count, CAP);
        float cs[8]; int ci[8];
        #pragma unroll
        for (int j = 0; j < 8; ++j) {
            const int p = lane + 64 * j;
            const bool ok = p < cnt;
            cs[j] = ok ? c_score[p] : -2.0f;
            ci[j] = ok ? c_idx[p]   : 0x7fffffff;
        }
        const int outbase = (b * TILES_PER_B + blockIdx.y * XBANDS + blockIdx.x) * KTOP;
        #pragma unroll
        for (int k = 0; k < KTOP; ++k) {
            float bs = cs[0]; int bi = ci[0];
            #pragma unroll
            for (int j = 1; j < 8; ++j)
                if (cs[j] > bs || (cs[j] == bs && ci[j] < bi)) { bs = cs[j]; bi = ci[j]; }
            #pragma unroll
            for (int off = 32; off >= 1; off >>= 1) {
                const float os = __shfl_xor(bs, off);
                const int   oi = __shfl_xor(bi, off);
                if (os > bs || (os == bs && oi < bi)) { bs = os; bi = oi; }
            }
            if (lane == 0) { bscore[outbase + k] = bs; bidx[outbase + k] = bi; }
            #pragma unroll
            for (int j = 0; j < 8; ++j) if (ci[j] == bi) cs[j] = -3.0f;
        }
    }
}

// ---------------- Kernel 2: per-batch merge of 180 entries -> top-6 (1 wave) ----------------
__global__ __launch_bounds__(64) void topk_kernel(const float* __restrict__ bscore,
                                                  const int* __restrict__ bidx,
                                                  float* __restrict__ out,
                                                  int B) {
    const int t = threadIdx.x;   // 64 threads
    const int b = blockIdx.x;

    float s0 = -9.0f, s1 = -9.0f, s2 = -9.0f;
    int   i0 = 0x7fffffff, i1 = 0x7fffffff, i2 = 0x7fffffff;
    if (t < MENT)       { s0 = bscore[b * MENT + t];       i0 = bidx[b * MENT + t]; }
    if (t + 64 < MENT)  { s1 = bscore[b * MENT + t + 64];  i1 = bidx[b * MENT + t + 64]; }
    if (t + 128 < MENT) { s2 = bscore[b * MENT + t + 128]; i2 = bidx[b * MENT + t + 128]; }

    float my_s = -9.0f; int my_i = 0x7fffffff;
    #pragma unroll
    for (int k = 0; k < KTOP; ++k) {
        float bs = s0; int bi = i0;
        if (s1 > bs || (s1 == bs && i1 < bi)) { bs = s1; bi = i1; }
        if (s2 > bs || (s2 == bs && i2 < bi)) { bs = s2; bi = i2; }
        #pragma unroll
        for (int off = 32; off >= 1; off >>= 1) {
            const float os = __shfl_xor(bs, off);
            const int   oi = __shfl_xor(bi, off);
            if (os > bs || (os == bs && oi < bi)) { bs = os; bi = oi; }
        }
        if (t == k) { my_s = bs; my_i = bi; }   // thread k owns result k
        if (i0 == bi) s0 = -9.0f;
        if (i1 == bi) s1 = -9.0f;
        if (i2 == bi) s2 = -9.0f;
    }

    if (t < KTOP) {
        const bool valid = (my_s > CONF) && (my_i >= 0) && (my_i < HH * WW);
        const int id = valid ? my_i : 0;
        const int xi = id % WW;
        const int yi = id / WW;
        const float px = valid ? xi * (1.0f / (WW - 1)) : -1.0f;
        const float py = valid ? yi * (1.0f / (HH - 1)) : -1.0f;
        out[(size_t)b * KTOP * 2 + t * 2 + 0] = px;
        out[(size_t)b * KTOP * 2 + t * 2 + 1] = py;
        out[(size_t)B * KTOP * 2 + (size_t)b * KTOP + t] = valid ? my_s : 0.0f;
    }
}

extern "C" void kernel_launch(void* const* d_in, const int* in_sizes, int n_in,
                              void* d_out, int out_size, void* d_ws, size_t ws_size,
                              hipStream_t stream) {
    const float* hm = (const float*)d_in[0];
    float* out = (float*)d_out;
    const int B = in_sizes[0] / (HH * WW);

    float* bscore = (float*)d_ws;
    int*   bidx   = (int*)((char*)d_ws + sizeof(float) * (size_t)B * MENT);

    dim3 grid1(XBANDS, YCH, B);
    peaks_kernel<<<grid1, NTHR, 0, stream>>>(hm, bscore, bidx);
    topk_kernel<<<B, 64, 0, stream>>>(bscore, bidx, out, B);
}